// Round 4
// baseline (287.088 us; speedup 1.0000x reference)
//
#include <hip/hip_runtime.h>
#include <hip/hip_bf16.h>

// Shapes: B=1024, C=80, D_WORD=300 (pad 384), J=8000, IMG_CH=2048
// out = feature @ H^T + r;  H = P @ W_img;  r = P @ b_img
// P = x2 @ W_cls^T + b_cls; x2 = adj @ t2; t2 = x1 @ Wgc2; x1 = leaky(adj @ t1); t1 = x0 @ Wgc1

typedef __bf16 bf16_t;
typedef __bf16 bf16x8 __attribute__((ext_vector_type(8)));
typedef float f32x4 __attribute__((ext_vector_type(4)));

#define MFMA16(a, b, c) __builtin_amdgcn_mfma_f32_16x16x32_bf16((a), (b), (c), 0, 0, 0)

// async global->LDS, 16B per lane; LDS dest is wave-uniform base + lane*16 (linear)
#define GLOAD_LDS16(g, l)                                     \
  __builtin_amdgcn_global_load_lds(                           \
      (const __attribute__((address_space(1))) void*)(g),     \
      (__attribute__((address_space(3))) void*)(l), 16, 0, 0)

// Issue-order pin: vmcnt counting is only valid if machine order == source order.
#define PIN()                                   \
  do {                                          \
    asm volatile("" ::: "memory");              \
    __builtin_amdgcn_sched_barrier(0);          \
  } while (0)

__device__ inline bf16x8 cvt8(float4 a, float4 b) {
  bf16x8 v;
  v[0] = (bf16_t)a.x; v[1] = (bf16_t)a.y; v[2] = (bf16_t)a.z; v[3] = (bf16_t)a.w;
  v[4] = (bf16_t)b.x; v[5] = (bf16_t)b.y; v[6] = (bf16_t)b.z; v[7] = (bf16_t)b.w;
  return v;
}

// ---- adj[i][j] = D[i]*D[j]*A[j][i], D = rsqrt(rowsum(A)) ----
__global__ void k_adj(const float* __restrict__ A, float* __restrict__ adj) {
  __shared__ float Dv[80];
  int tid = threadIdx.x;
  if (tid < 80) {
    float s = 0.f;
    #pragma unroll 4
    for (int j = 0; j < 80; ++j) s += A[tid * 80 + j];
    Dv[tid] = rsqrtf(s);
  }
  __syncthreads();
  for (int idx = tid; idx < 6400; idx += blockDim.x) {
    int i = idx / 80, j = idx % 80;
    adj[idx] = Dv[i] * Dv[j] * A[j * 80 + i];
  }
}

// ---- x0b[c][k] = bf16(inp0[c][k]) for k<300 else 0 : [80,384] ----
__global__ void k_cvt0(const float* __restrict__ inp0, bf16_t* __restrict__ x0b) {
  int idx = blockIdx.x * blockDim.x + threadIdx.x;  // 80*384 = 30720
  if (idx < 30720) {
    int c = idx / 384, k = idx % 384;
    x0b[idx] = (k < 300) ? (bf16_t)inp0[c * 300 + k] : (bf16_t)0.f;
  }
}

// ---- t1 += x0 @ Wgc1 : [80,1024], K=384(padded); k-split x3 for occupancy ----
// grid 192 = 64 n-chunks(16) x 3 k-chunks(128); atomics into zeroed t1.
__global__ __launch_bounds__(256, 2) void k_gc1m(
    const bf16_t* __restrict__ x0b, const float* __restrict__ Wgc1,
    float* __restrict__ t1) {
  int tid = threadIdx.x;
  int w = tid >> 6, l = tid & 63;
  int ln = l & 15, q = l >> 4;
  int n0 = (blockIdx.x & 63) * 16;
  int kc = blockIdx.x >> 6;              // 0..2
  int kq = kc * 128 + w * 32 + q * 8;

  __shared__ float red[4][80][16];
  f32x4 acc[5] = {};
  bf16x8 bfrag;
  #pragma unroll
  for (int jj = 0; jj < 8; ++jj) {
    int k = kq + jj;
    int kcl = k < 300 ? k : 299;
    float wv = Wgc1[kcl * 1024 + n0 + ln];
    bfrag[jj] = (bf16_t)(k < 300 ? wv : 0.f);
  }
  #pragma unroll
  for (int mt = 0; mt < 5; ++mt) {
    bf16x8 afrag = *(const bf16x8*)(x0b + (size_t)(mt * 16 + ln) * 384 + kq);
    acc[mt] = MFMA16(afrag, bfrag, acc[mt]);
  }
  #pragma unroll
  for (int mt = 0; mt < 5; ++mt)
    #pragma unroll
    for (int reg = 0; reg < 4; ++reg)
      red[w][mt * 16 + q * 4 + reg][ln] = acc[mt][reg];
  __syncthreads();
  for (int o = tid; o < 1280; o += 256) {
    int c = o >> 4, nn = o & 15;
    atomicAdd(&t1[c * 1024 + n0 + nn],
              red[0][c][nn] + red[1][c][nn] + red[2][c][nn] + red[3][c][nn]);
  }
}

// ---- x1b = bf16(leaky_relu(adj @ t1, 0.2)) : [80,1024] ----
__global__ void k_adjmul_leaky(const float* __restrict__ adj, const float* __restrict__ t1,
                               bf16_t* __restrict__ x1b) {
  int idx = blockIdx.x * blockDim.x + threadIdx.x;  // 81920
  int c = idx >> 10, n = idx & 1023;
  const float* ar = adj + c * 80;
  float acc = 0.f;
  #pragma unroll 4
  for (int cc = 0; cc < 80; ++cc) acc += ar[cc] * t1[cc * 1024 + n];
  x1b[idx] = (bf16_t)(acc > 0.f ? acc : 0.2f * acc);
}

// ---- t2 += x1 @ Wgc2 : [80,2048], K=1024 ----
// grid 512 = 32 n-chunks(64) x 16 k-chunks(64); 2 async 32k stages.
// (256,2): give the register allocator room so a0/a1 + staging stay in regs.
__global__ __launch_bounds__(256, 2) void k_gc2m(
    const bf16_t* __restrict__ x1b, const float* __restrict__ Wgc2,
    float* __restrict__ t2) {
  int tid = threadIdx.x;
  int w = tid >> 6, l = tid & 63;
  int ln = l & 15, q = l >> 4;
  int nc = blockIdx.x & 31, kc = blockIdx.x >> 5;

  __shared__ float BsF[2 * 2048];  // 2 buffers x 32k x 64n fp32 = 16 KB (linear)
  auto stage = [&](int b, int k0) {
    #pragma unroll
    for (int it = 0; it < 2; ++it) {
      int slot = tid + it * 256;  // 512 slots = 32k x (16 x float4)
      int kr = slot >> 4, nq = slot & 15;
      const float* src = Wgc2 + (size_t)(k0 + kr) * 2048 + nc * 64 + nq * 4;
      float* dst = BsF + b * 2048 + slot * 4;
      GLOAD_LDS16(src, dst);
    }
  };

  int kb = kc * 64;
  bf16x8 a0[5], a1[5];
  #pragma unroll
  for (int mt = 0; mt < 5; ++mt)
    a0[mt] = *(const bf16x8*)(x1b + (size_t)(mt * 16 + ln) * 1024 + kb + q * 8);
  PIN();
  stage(0, kb);
  PIN();
  stage(1, kb + 32);
  PIN();
  #pragma unroll
  for (int mt = 0; mt < 5; ++mt)
    a1[mt] = *(const bf16x8*)(x1b + (size_t)(mt * 16 + ln) * 1024 + kb + 32 + q * 8);
  PIN();

  f32x4 acc[5] = {};
  // stage 0: after-B0 in flight = B1(2)+A1(5) = 7
  asm volatile("s_waitcnt vmcnt(7)" ::: "memory");
  PIN();
  __builtin_amdgcn_s_barrier();
  PIN();
  {
    bf16x8 bfrag;
    #pragma unroll
    for (int jj = 0; jj < 8; ++jj) bfrag[jj] = (bf16_t)BsF[(q * 8 + jj) * 64 + w * 16 + ln];
    #pragma unroll
    for (int mt = 0; mt < 5; ++mt) acc[mt] = MFMA16(a0[mt], bfrag, acc[mt]);
  }
  // stage 1: after-B1 = A1(5) = 5
  asm volatile("s_waitcnt vmcnt(5)" ::: "memory");
  PIN();
  __builtin_amdgcn_s_barrier();
  PIN();
  {
    bf16x8 bfrag;
    #pragma unroll
    for (int jj = 0; jj < 8; ++jj)
      bfrag[jj] = (bf16_t)BsF[2048 + (q * 8 + jj) * 64 + w * 16 + ln];
    #pragma unroll
    for (int mt = 0; mt < 5; ++mt) acc[mt] = MFMA16(a1[mt], bfrag, acc[mt]);
  }

  #pragma unroll
  for (int mt = 0; mt < 5; ++mt)
    #pragma unroll
    for (int reg = 0; reg < 4; ++reg)
      atomicAdd(&t2[(size_t)(mt * 16 + q * 4 + reg) * 2048 + nc * 64 + w * 16 + ln],
                acc[mt][reg]);
}

// ---- x2 = bf16(adj @ t2) : [80,2048] ----
__global__ void k_adjmul_bf16(const float* __restrict__ adj, const float* __restrict__ t2,
                              bf16_t* __restrict__ x2) {
  int idx = blockIdx.x * blockDim.x + threadIdx.x;  // 163840
  int c = idx >> 11, n = idx & 2047;
  const float* ar = adj + c * 80;
  float acc = 0.f;
  #pragma unroll 4
  for (int cc = 0; cc < 80; ++cc) acc += ar[cc] * t2[cc * 2048 + n];
  x2[idx] = (bf16_t)acc;
}

// ---- P = bf16(x2 @ W_cls^T + b_cls) : [80,8000]; r[c] += b_img . P[c,:] ----
// R4: (256,2) register budget + copy-free ping-pong prefetch (aF/bA/bB indexed
// [ks&1] under full unroll -> compile-time, no end-of-iter register copies
// that would force a drain of the newest loads).
__global__ __launch_bounds__(256, 2) void k_clsproj(
    const float* __restrict__ Wcls, const float* __restrict__ bcls,
    const float* __restrict__ bimg, const bf16_t* __restrict__ x2,
    bf16_t* __restrict__ P, float* __restrict__ r) {
  int tid = threadIdx.x;
  int w = tid >> 6, l = tid & 63;
  int ln = l & 15, q = l >> 4;
  int j0 = blockIdx.x * 16;
  size_t jrow = (size_t)(j0 + ln) * 2048;

  __shared__ float red[4][80][16];
  __shared__ float rloc[80];
  if (tid < 80) rloc[tid] = 0.f;

  f32x4 acc[5] = {};
  int kbase = w * 512 + q * 8;

  float4 bA[2], bB[2];
  bf16x8 aF[2][5];
  {
    const float4* bp = (const float4*)(Wcls + jrow + kbase);
    bA[0] = bp[0]; bB[0] = bp[1];
    #pragma unroll
    for (int mt = 0; mt < 5; ++mt)
      aF[0][mt] = *(const bf16x8*)(x2 + (size_t)(mt * 16 + ln) * 2048 + kbase);
  }
  #pragma unroll
  for (int ks = 0; ks < 16; ++ks) {
    int cur = ks & 1, nxt = cur ^ 1;
    if (ks < 15) {
      int kq = kbase + (ks + 1) * 32;
      const float4* bp = (const float4*)(Wcls + jrow + kq);
      bA[nxt] = bp[0]; bB[nxt] = bp[1];
      #pragma unroll
      for (int mt = 0; mt < 5; ++mt)
        aF[nxt][mt] = *(const bf16x8*)(x2 + (size_t)(mt * 16 + ln) * 2048 + kq);
    }
    bf16x8 bfrag = cvt8(bA[cur], bB[cur]);
    #pragma unroll
    for (int mt = 0; mt < 5; ++mt) acc[mt] = MFMA16(aF[cur][mt], bfrag, acc[mt]);
  }
  #pragma unroll
  for (int mt = 0; mt < 5; ++mt)
    #pragma unroll
    for (int reg = 0; reg < 4; ++reg)
      red[w][mt * 16 + q * 4 + reg][ln] = acc[mt][reg];
  __syncthreads();

  for (int o = tid; o < 1280; o += 256) {
    int c = o >> 4, jj = o & 15;
    float v = red[0][c][jj] + red[1][c][jj] + red[2][c][jj] + red[3][c][jj] + bcls[j0 + jj];
    P[(size_t)c * 8000 + j0 + jj] = (bf16_t)v;
    atomicAdd(&rloc[c], bimg[j0 + jj] * v);
  }
  __syncthreads();
  if (tid < 80) atomicAdd(&r[tid], rloc[tid]);
}

// ---- H[c][n] += sum_j P[c][j]*W_img[j][n] ----
// Barrier-free wave-private (R3 structure) + R4 fixes: (256,2) register
// budget (R2/R3 ran at 48-60 VGPR -> loads serialized), copy-free ping-pong
// aF[s&1], grid 400->800 (jc=50 chunks of 160j, 5 stages) for occupancy.
// Per-wave pinned FIFO: A0 B0 B1 | [A1 B2] [A2 B3] [A3 B4] [A4] []
//   wait-B(s): s<3 -> 13 (B(s+1)4+A(s+1)5+B(s+2)4); s=3 -> 9; s=4 -> 5.
__global__ __launch_bounds__(256, 2) void k_hmat(
    const float* __restrict__ Wimg, const bf16_t* __restrict__ P, float* __restrict__ H) {
  int tid = threadIdx.x;
  int w = tid >> 6, l = tid & 63;
  int ln = l & 15, q = l >> 4;
  int jc = blockIdx.x >> 4, ncg = blockIdx.x & 15;  // jc 0..49
  int jbase = jc * 160;
  int n0 = (ncg * 4 + w) * 32;

  __shared__ float Bs[4 * 3 * 1024];  // 4 waves x ring-3 x (32j x 32n fp32) = 48 KB
  float* Bw = Bs + w * 3072;

  auto stage = [&](int buf, int jt) {
    #pragma unroll
    for (int it = 0; it < 4; ++it) {
      int row = it * 8 + (l >> 3);          // j-row 0..31
      const float* src = Wimg + (size_t)(jt + row) * 2048 + n0 + (l & 7) * 4;
      float* dst = Bw + buf * 1024 + it * 256 + l * 4;  // linear: lane*16B
      GLOAD_LDS16(src, dst);
    }
  };
  auto loadA = [&](bf16x8* a, int jt) {
    #pragma unroll
    for (int mt = 0; mt < 5; ++mt)
      a[mt] = *(const bf16x8*)(P + (size_t)(mt * 16 + ln) * 8000 + jt + q * 8);
  };

  f32x4 acc[5][2] = {};
  bf16x8 aF[2][5];

  loadA(aF[0], jbase);     // A(0)
  PIN();
  stage(0, jbase);         // B(0)
  PIN();
  stage(1, jbase + 32);    // B(1)
  PIN();

  #pragma unroll
  for (int s = 0; s < 5; ++s) {
    if (s < 4) {
      loadA(aF[(s + 1) & 1], jbase + (s + 1) * 32);  // A(s+1)
      PIN();
    }
    if (s < 3) {
      stage((s + 2) % 3, jbase + (s + 2) * 32);      // B(s+2)
      PIN();
    }
    if (s < 3)       asm volatile("s_waitcnt vmcnt(13)" ::: "memory");
    else if (s == 3) asm volatile("s_waitcnt vmcnt(9)"  ::: "memory");
    else             asm volatile("s_waitcnt vmcnt(5)"  ::: "memory");
    PIN();  // no barrier — buffer is wave-private
    const float* Bc = Bw + (s % 3) * 1024;
    bf16x8 bfrag[2];
    #pragma unroll
    for (int nt = 0; nt < 2; ++nt)
      #pragma unroll
      for (int jj = 0; jj < 8; ++jj)
        bfrag[nt][jj] = (bf16_t)Bc[(q * 8 + jj) * 32 + nt * 16 + ln];
    #pragma unroll
    for (int mt = 0; mt < 5; ++mt)
      #pragma unroll
      for (int nt = 0; nt < 2; ++nt)
        acc[mt][nt] = MFMA16(aF[s & 1][mt], bfrag[nt], acc[mt][nt]);
    PIN();  // keep cvt/MFMA ahead of next iter's restage of buf[s%3]
  }

  #pragma unroll
  for (int mt = 0; mt < 5; ++mt)
    #pragma unroll
    for (int nt = 0; nt < 2; ++nt)
      #pragma unroll
      for (int reg = 0; reg < 4; ++reg)
        atomicAdd(&H[(size_t)(mt * 16 + q * 4 + reg) * 2048 + n0 + nt * 16 + ln],
                  acc[mt][nt][reg]);
}

// ---- out[b][c] += sum_k feature[b][k]*H[c][k]  (+ r[c] once) ----
// grid 512 = 16 m-groups(64) x 32 k-chunks(64)
__global__ __launch_bounds__(256, 2) void k_out(
    const float* __restrict__ feat, const float* __restrict__ H,
    const float* __restrict__ r, float* __restrict__ out) {
  int tid = threadIdx.x;
  int w = tid >> 6, l = tid & 63;
  int ln = l & 15, q = l >> 4;
  int mg = blockIdx.x & 15, kc = blockIdx.x >> 4;  // kc 0..31, 64 k each
  int m0 = mg * 64 + w * 16;
  size_t frow = (size_t)(m0 + ln) * 2048;

  f32x4 acc[5] = {};
  int kbase = kc * 64 + q * 8;
  #pragma unroll
  for (int ks = 0; ks < 2; ++ks) {
    int kq = kbase + ks * 32;
    const float4* ap = (const float4*)(feat + frow + kq);
    bf16x8 afrag = cvt8(ap[0], ap[1]);
    #pragma unroll
    for (int nt = 0; nt < 5; ++nt) {
      const float4* hp = (const float4*)(H + (size_t)(nt * 16 + ln) * 2048 + kq);
      bf16x8 bfrag = cvt8(hp[0], hp[1]);
      acc[nt] = MFMA16(afrag, bfrag, acc[nt]);
    }
  }
  #pragma unroll
  for (int nt = 0; nt < 5; ++nt)
    #pragma unroll
    for (int reg = 0; reg < 4; ++reg) {
      int b = m0 + q * 4 + reg;
      int c = nt * 16 + ln;
      float v = acc[nt][reg];
      if (kc == 0) v += r[c];
      atomicAdd(&out[b * 80 + c], v);
    }
}

extern "C" void kernel_launch(void* const* d_in, const int* in_sizes, int n_in,
                              void* d_out, int out_size, void* d_ws, size_t ws_size,
                              hipStream_t stream) {
  const float* feature = (const float*)d_in[0];
  const float* inp     = (const float*)d_in[1];  // [1,80,300]
  const float* A       = (const float*)d_in[2];
  const float* Wgc1    = (const float*)d_in[3];
  const float* Wgc2    = (const float*)d_in[4];
  const float* Wimg    = (const float*)d_in[5];
  const float* bimg    = (const float*)d_in[6];
  const float* Wcls    = (const float*)d_in[7];
  const float* bcls    = (const float*)d_in[8];
  float* out = (float*)d_out;

  char* ws = (char*)d_ws;
  float*  adj = (float*)(ws + 0);         //  80x80    fp32     25,600
  float*  t1  = (float*)(ws + 25600);     //  80x1024  fp32    327,680
  bf16_t* x1b = (bf16_t*)(ws + 353280);   //  80x1024  bf16    163,840
  float*  t2  = (float*)(ws + 517120);    //  80x2048  fp32    655,360
  bf16_t* x2  = (bf16_t*)(ws + 1172480);  //  80x2048  bf16    327,680
  bf16_t* P   = (bf16_t*)(ws + 1500160);  //  80x8000  bf16  1,280,000
  float*  H   = (float*)(ws + 2780160);   //  80x2048  fp32    655,360
  float*  r   = (float*)(ws + 3435520);   //  80       fp32        320
  bf16_t* x0b = (bf16_t*)(ws + 3435840);  //  80x384   bf16     61,440

  hipMemsetAsync(t1, 0, 80 * 1024 * 4, stream);
  hipMemsetAsync(t2, 0, 80 * 2048 * 4, stream);
  hipMemsetAsync(H, 0, 80 * 2048 * 4, stream);
  hipMemsetAsync(r, 0, 80 * 4, stream);
  hipMemsetAsync(out, 0, 1024 * 80 * 4, stream);

  k_adj<<<1, 128, 0, stream>>>(A, adj);
  k_cvt0<<<120, 256, 0, stream>>>(inp, x0b);
  k_gc1m<<<192, 256, 0, stream>>>(x0b, Wgc1, t1);
  k_adjmul_leaky<<<320, 256, 0, stream>>>(adj, t1, x1b);
  k_gc2m<<<512, 256, 0, stream>>>(x1b, Wgc2, t2);
  k_adjmul_bf16<<<640, 256, 0, stream>>>(adj, t2, x2);
  k_clsproj<<<500, 256, 0, stream>>>(Wcls, bcls, bimg, x2, P, r);
  k_hmat<<<800, 256, 0, stream>>>(Wimg, P, H);
  k_out<<<512, 256, 0, stream>>>(feature, H, r, out);
}

// Round 5
// 284.957 us; speedup vs baseline: 1.0075x; 1.0075x over previous
//
#include <hip/hip_runtime.h>
#include <hip/hip_bf16.h>

// Shapes: B=1024, C_CLS=80, D_WORD=300 (pad 384), J=8000, IMG_CH=2048
// out = feature @ H^T + r;  H = P @ W_img;  r = P @ b_img
// P = x2 @ W_cls^T + b_cls; x2 = adj @ t2; t2 = x1 @ Wgc2; x1 = leaky(adj @ t1); t1 = x0 @ Wgc1

typedef __bf16 bf16_t;
typedef __bf16 bf16x8 __attribute__((ext_vector_type(8)));
typedef float f32x4 __attribute__((ext_vector_type(4)));

#define MFMA16(a, b, c) __builtin_amdgcn_mfma_f32_16x16x32_bf16((a), (b), (c), 0, 0, 0)

// Issue-order pin: keeps the compiler from sinking prefetch loads to their
// uses (R4 post-mortem: unpinned ping-pong collapsed to 36 VGPRs = serial).
#define PIN()                                   \
  do {                                          \
    asm volatile("" ::: "memory");              \
    __builtin_amdgcn_sched_barrier(0);          \
  } while (0)

// counted wait with literal immediate (token-pasted)
#define WAITV(n) asm volatile("s_waitcnt vmcnt(" #n ")" ::: "memory")

__device__ inline bf16x8 cvt8(float4 a, float4 b) {
  bf16x8 v;
  v[0] = (bf16_t)a.x; v[1] = (bf16_t)a.y; v[2] = (bf16_t)a.z; v[3] = (bf16_t)a.w;
  v[4] = (bf16_t)b.x; v[5] = (bf16_t)b.y; v[6] = (bf16_t)b.z; v[7] = (bf16_t)b.w;
  return v;
}

// ---- adj[i][j] = D[i]*D[j]*A[j][i], D = rsqrt(rowsum(A)) ----
__global__ void k_adj(const float* __restrict__ A, float* __restrict__ adj) {
  __shared__ float Dv[80];
  int tid = threadIdx.x;
  if (tid < 80) {
    float s = 0.f;
    #pragma unroll 4
    for (int j = 0; j < 80; ++j) s += A[tid * 80 + j];
    Dv[tid] = rsqrtf(s);
  }
  __syncthreads();
  for (int idx = tid; idx < 6400; idx += blockDim.x) {
    int i = idx / 80, j = idx % 80;
    adj[idx] = Dv[i] * Dv[j] * A[j * 80 + i];
  }
}

// ---- x0b[c][k] = bf16(inp0[c][k]) for k<300 else 0 : [80,384] ----
__global__ void k_cvt0(const float* __restrict__ inp0, bf16_t* __restrict__ x0b) {
  int idx = blockIdx.x * blockDim.x + threadIdx.x;  // 80*384 = 30720
  if (idx < 30720) {
    int c = idx / 384, k = idx % 384;
    x0b[idx] = (k < 300) ? (bf16_t)inp0[c * 300 + k] : (bf16_t)0.f;
  }
}

// ---- t1 += x0 @ Wgc1 : [80,1024], K=384(padded); k-split x3 ----
__global__ __launch_bounds__(256, 2) void k_gc1m(
    const bf16_t* __restrict__ x0b, const float* __restrict__ Wgc1,
    float* __restrict__ t1) {
  int tid = threadIdx.x;
  int w = tid >> 6, l = tid & 63;
  int ln = l & 15, q = l >> 4;
  int n0 = (blockIdx.x & 63) * 16;
  int kc = blockIdx.x >> 6;              // 0..2
  int kq = kc * 128 + w * 32 + q * 8;

  __shared__ float red[4][80][16];
  f32x4 acc[5] = {};
  bf16x8 bfrag;
  #pragma unroll
  for (int jj = 0; jj < 8; ++jj) {
    int k = kq + jj;
    int kcl = k < 300 ? k : 299;
    float wv = Wgc1[kcl * 1024 + n0 + ln];
    bfrag[jj] = (bf16_t)(k < 300 ? wv : 0.f);
  }
  #pragma unroll
  for (int mt = 0; mt < 5; ++mt) {
    bf16x8 afrag = *(const bf16x8*)(x0b + (size_t)(mt * 16 + ln) * 384 + kq);
    acc[mt] = MFMA16(afrag, bfrag, acc[mt]);
  }
  #pragma unroll
  for (int mt = 0; mt < 5; ++mt)
    #pragma unroll
    for (int reg = 0; reg < 4; ++reg)
      red[w][mt * 16 + q * 4 + reg][ln] = acc[mt][reg];
  __syncthreads();
  for (int o = tid; o < 1280; o += 256) {
    int c = o >> 4, nn = o & 15;
    atomicAdd(&t1[c * 1024 + n0 + nn],
              red[0][c][nn] + red[1][c][nn] + red[2][c][nn] + red[3][c][nn]);
  }
}

// ---- x1b = bf16(leaky_relu(adj @ t1, 0.2)) : [80,1024] ----
__global__ void k_adjmul_leaky(const float* __restrict__ adj, const float* __restrict__ t1,
                               bf16_t* __restrict__ x1b) {
  int idx = blockIdx.x * blockDim.x + threadIdx.x;  // 81920
  int c = idx >> 10, n = idx & 1023;
  const float* ar = adj + c * 80;
  float acc = 0.f;
  #pragma unroll 4
  for (int cc = 0; cc < 80; ++cc) acc += ar[cc] * t1[cc * 1024 + n];
  x1b[idx] = (bf16_t)(acc > 0.f ? acc : 0.2f * acc);
}

// ---- t2 += x1 @ Wgc2 : [80,2048], K=1024 ----
// R5: no LDS, no barriers. Direct-fragment streamer, prefetch-ALL (4 steps).
// grid 256 = 32 n-groups(64; wave=16n) x 8 k-chunks(128 = 4 steps of 32k).
// Issue: [A0..A3: 4x5 bf16x8][B0..B3: 4x8 dword]; waits 24/16/8/0.
__global__ __launch_bounds__(256, 2) void k_gc2m(
    const bf16_t* __restrict__ x1b, const float* __restrict__ Wgc2,
    float* __restrict__ t2) {
  int tid = threadIdx.x;
  int w = tid >> 6, l = tid & 63;
  int ln = l & 15, q = l >> 4;
  int ng = blockIdx.x & 31, kc = blockIdx.x >> 5;
  int n0 = ng * 64 + w * 16;
  int k0 = kc * 128;

  const bf16_t* pA[5];
  #pragma unroll
  for (int mt = 0; mt < 5; ++mt)
    pA[mt] = x1b + (size_t)(mt * 16 + ln) * 1024 + k0 + q * 8;
  const float* pB = Wgc2 + (size_t)(k0 + q * 8) * 2048 + n0 + ln;

  bf16x8 ar[4][5];
  float bdw[4][8];
  f32x4 acc[5] = {};

  #pragma unroll
  for (int s = 0; s < 4; ++s) {
    #pragma unroll
    for (int mt = 0; mt < 5; ++mt) ar[s][mt] = *(const bf16x8*)(pA[mt] + s * 32);
    PIN();
  }
  #pragma unroll
  for (int s = 0; s < 4; ++s) {
    #pragma unroll
    for (int jj = 0; jj < 8; ++jj) bdw[s][jj] = pB[(size_t)(s * 32 + jj) * 2048];
    PIN();
  }

  #pragma unroll
  for (int s = 0; s < 4; ++s) {
    if (s == 0) WAITV(24); else if (s == 1) WAITV(16);
    else if (s == 2) WAITV(8); else WAITV(0);
    bf16x8 bfrag;
    #pragma unroll
    for (int jj = 0; jj < 8; ++jj) bfrag[jj] = (bf16_t)bdw[s][jj];
    #pragma unroll
    for (int mt = 0; mt < 5; ++mt) acc[mt] = MFMA16(ar[s][mt], bfrag, acc[mt]);
    PIN();
  }

  #pragma unroll
  for (int mt = 0; mt < 5; ++mt)
    #pragma unroll
    for (int reg = 0; reg < 4; ++reg)
      atomicAdd(&t2[(size_t)(mt * 16 + q * 4 + reg) * 2048 + n0 + ln],
                acc[mt][reg]);
}

// ---- x2 = bf16(adj @ t2) : [80,2048] ----
__global__ void k_adjmul_bf16(const float* __restrict__ adj, const float* __restrict__ t2,
                              bf16_t* __restrict__ x2) {
  int idx = blockIdx.x * blockDim.x + threadIdx.x;  // 163840
  int c = idx >> 11, n = idx & 2047;
  const float* ar = adj + c * 80;
  float acc = 0.f;
  #pragma unroll 4
  for (int cc = 0; cc < 80; ++cc) acc += ar[cc] * t2[cc * 2048 + n];
  x2[idx] = (bf16_t)acc;
}

// ---- P = bf16(x2 @ W_cls^T + b_cls) : [80,8000] ----
// R5 role-swap: m=j (A from Wcls, contiguous fp32 stream), n=c (B from x2,
// contiguous bf16x8, L3-hot). Full K=2048 per block (64 steps) -> no atomics.
// grid 250 x 128 thr; wave owns 16 j-rows. A-ring 8 slots (4 deep in flight),
// B-ring 4 (2 deep). All issues PINned; exact counted vmcnt:
//   i=0:12, 1..59:14, 60:12, 61:10, 62:5, 63:0.
// Epilogue: per-wave LDS transpose (P^T frags -> row-major P) + bcls.
__global__ __launch_bounds__(128, 2) void k_clsproj(
    const float* __restrict__ Wcls, const float* __restrict__ bcls,
    const bf16_t* __restrict__ x2, bf16_t* __restrict__ P) {
  int tid = threadIdx.x;
  int w = tid >> 6, l = tid & 63;
  int ln = l & 15, q = l >> 4;
  int j0w = blockIdx.x * 32 + w * 16;

  __shared__ float sm[2][16][84];

  const float* pA = Wcls + (size_t)(j0w + ln) * 2048 + q * 8;
  const bf16_t* pB[5];
  #pragma unroll
  for (int ct = 0; ct < 5; ++ct)
    pB[ct] = x2 + (size_t)(ct * 16 + ln) * 2048 + q * 8;

  float4 ar[8][2];
  bf16x8 br[4][5];
  f32x4 acc[5] = {};

  // prologue: A(0..3), B(0..1)
  #pragma unroll
  for (int s = 0; s < 4; ++s) {
    ar[s][0] = *(const float4*)(pA + s * 32);
    ar[s][1] = *(const float4*)(pA + s * 32 + 4);
    PIN();
  }
  #pragma unroll
  for (int s = 0; s < 2; ++s) {
    #pragma unroll
    for (int ct = 0; ct < 5; ++ct) br[s][ct] = *(const bf16x8*)(pB[ct] + s * 32);
    PIN();
  }

  #pragma unroll
  for (int i = 0; i < 64; ++i) {
    if (i <= 59) {  // issue A(i+4)
      ar[(i + 4) & 7][0] = *(const float4*)(pA + (i + 4) * 32);
      ar[(i + 4) & 7][1] = *(const float4*)(pA + (i + 4) * 32 + 4);
      PIN();
    }
    if (i <= 61) {  // issue B(i+2)
      #pragma unroll
      for (int ct = 0; ct < 5; ++ct)
        br[(i + 2) & 3][ct] = *(const bf16x8*)(pB[ct] + (i + 2) * 32);
      PIN();
    }
    if (i == 0) WAITV(12);
    else if (i < 60) WAITV(14);
    else if (i == 60) WAITV(12);
    else if (i == 61) WAITV(10);
    else if (i == 62) WAITV(5);
    else WAITV(0);
    bf16x8 af = cvt8(ar[i & 7][0], ar[i & 7][1]);
    #pragma unroll
    for (int ct = 0; ct < 5; ++ct) acc[ct] = MFMA16(af, br[i & 3][ct], acc[ct]);
    PIN();
  }

  // transpose via wave-private LDS: lane holds P^T[j=q*4+reg][c=ct*16+ln]
  #pragma unroll
  for (int ct = 0; ct < 5; ++ct)
    #pragma unroll
    for (int reg = 0; reg < 4; ++reg)
      sm[w][q * 4 + reg][ct * 16 + ln] = acc[ct][reg];
  PIN();
  asm volatile("s_waitcnt lgkmcnt(0)" ::: "memory");
  PIN();
  for (int o = l; o < 1280; o += 64) {
    int c = o >> 4, jj = o & 15;
    float v = sm[w][jj][c] + bcls[j0w + jj];
    P[(size_t)c * 8000 + j0w + jj] = (bf16_t)v;
  }
}

// ---- r[c] = sum_j bimg[j] * P[c][j] ----
__global__ __launch_bounds__(256) void k_rvec(
    const bf16_t* __restrict__ P, const float* __restrict__ bimg,
    float* __restrict__ r) {
  int c = blockIdx.x;  // 0..79
  int tid = threadIdx.x;
  float partial = 0.f;
  for (int ch = tid; ch < 1000; ch += 256) {
    bf16x8 p = *(const bf16x8*)(P + (size_t)c * 8000 + ch * 8);
    const float4* b = (const float4*)(bimg + ch * 8);
    float4 b0 = b[0], b1 = b[1];
    partial += (float)p[0] * b0.x + (float)p[1] * b0.y + (float)p[2] * b0.z +
               (float)p[3] * b0.w + (float)p[4] * b1.x + (float)p[5] * b1.y +
               (float)p[6] * b1.z + (float)p[7] * b1.w;
  }
  __shared__ float red[4];
  #pragma unroll
  for (int off = 32; off; off >>= 1) partial += __shfl_down(partial, off);
  if ((tid & 63) == 0) red[tid >> 6] = partial;
  __syncthreads();
  if (tid == 0) r[c] = red[0] + red[1] + red[2] + red[3];
}

// ---- H[c][n] += sum_j P[c][j]*Wimg[j][n] ----
// R5: no LDS, no barriers. A (P, L3-hot) bf16x8 frags; B (Wimg stream) as
// 16 scalar dwords/step (2 n-tiles), ring-4 (2 deep in flight).
// grid 400 = 25 j-chunks(320 = 10 steps) x 16 n-groups(128; wave=32n).
// Issue per iter: [A(i+2):5][B(i+2):16]; waits {37,42x7,21,0}.
__global__ __launch_bounds__(256, 2) void k_hmat(
    const float* __restrict__ Wimg, const bf16_t* __restrict__ P, float* __restrict__ H) {
  int tid = threadIdx.x;
  int w = tid >> 6, l = tid & 63;
  int ln = l & 15, q = l >> 4;
  int jc = blockIdx.x >> 4, ng = blockIdx.x & 15;  // jc 0..24
  int jbase = jc * 320;
  int n0 = ng * 128 + w * 32;

  const bf16_t* pA[5];
  #pragma unroll
  for (int mt = 0; mt < 5; ++mt)
    pA[mt] = P + (size_t)(mt * 16 + ln) * 8000 + jbase + q * 8;
  const float* pB = Wimg + (size_t)(jbase + q * 8) * 2048 + n0 + ln;

  bf16x8 arr[4][5];
  float bdw[4][16];
  f32x4 acc[5][2] = {};

  // prologue: A(0..1), B(0..1)
  #pragma unroll
  for (int s = 0; s < 2; ++s) {
    #pragma unroll
    for (int mt = 0; mt < 5; ++mt) arr[s][mt] = *(const bf16x8*)(pA[mt] + s * 32);
    PIN();
  }
  #pragma unroll
  for (int s = 0; s < 2; ++s) {
    #pragma unroll
    for (int nt = 0; nt < 2; ++nt)
      #pragma unroll
      for (int jj = 0; jj < 8; ++jj)
        bdw[s][nt * 8 + jj] = pB[(size_t)(s * 32 + jj) * 2048 + nt * 16];
    PIN();
  }

  #pragma unroll
  for (int i = 0; i < 10; ++i) {
    if (i <= 7) {
      #pragma unroll
      for (int mt = 0; mt < 5; ++mt)
        arr[(i + 2) & 3][mt] = *(const bf16x8*)(pA[mt] + (i + 2) * 32);
      PIN();
      #pragma unroll
      for (int nt = 0; nt < 2; ++nt)
        #pragma unroll
        for (int jj = 0; jj < 8; ++jj)
          bdw[(i + 2) & 3][nt * 8 + jj] = pB[(size_t)((i + 2) * 32 + jj) * 2048 + nt * 16];
      PIN();
    }
    if (i == 0) WAITV(37);
    else if (i < 8) WAITV(42);
    else if (i == 8) WAITV(21);
    else WAITV(0);
    bf16x8 bf0, bf1;
    #pragma unroll
    for (int jj = 0; jj < 8; ++jj) {
      bf0[jj] = (bf16_t)bdw[i & 3][jj];
      bf1[jj] = (bf16_t)bdw[i & 3][8 + jj];
    }
    #pragma unroll
    for (int mt = 0; mt < 5; ++mt) {
      acc[mt][0] = MFMA16(arr[i & 3][mt], bf0, acc[mt][0]);
      acc[mt][1] = MFMA16(arr[i & 3][mt], bf1, acc[mt][1]);
    }
    PIN();
  }

  #pragma unroll
  for (int mt = 0; mt < 5; ++mt)
    #pragma unroll
    for (int nt = 0; nt < 2; ++nt)
      #pragma unroll
      for (int reg = 0; reg < 4; ++reg)
        atomicAdd(&H[(size_t)(mt * 16 + q * 4 + reg) * 2048 + n0 + nt * 16 + ln],
                  acc[mt][nt][reg]);
}

// ---- out[b][c] += sum_k feature[b][k]*H[c][k]  (+ r[c] once) ----
// grid 512 = 16 m-groups(64) x 32 k-chunks(64 = 2 steps); prefetch-all.
__global__ __launch_bounds__(256, 2) void k_out(
    const float* __restrict__ feat, const float* __restrict__ H,
    const float* __restrict__ r, float* __restrict__ out) {
  int tid = threadIdx.x;
  int w = tid >> 6, l = tid & 63;
  int ln = l & 15, q = l >> 4;
  int mg = blockIdx.x & 15, kc = blockIdx.x >> 4;  // kc 0..31
  int m0 = mg * 64 + w * 16;
  int kbase = kc * 64 + q * 8;
  const float* pA = feat + (size_t)(m0 + ln) * 2048 + kbase;
  const float* pH = H + (size_t)ln * 2048 + kbase;

  float4 aw[2][2];
  float4 bw[2][5][2];
  f32x4 acc[5] = {};

  #pragma unroll
  for (int s = 0; s < 2; ++s) {
    aw[s][0] = *(const float4*)(pA + s * 32);
    aw[s][1] = *(const float4*)(pA + s * 32 + 4);
    PIN();
  }
  #pragma unroll
  for (int s = 0; s < 2; ++s) {
    #pragma unroll
    for (int nt = 0; nt < 5; ++nt) {
      bw[s][nt][0] = *(const float4*)(pH + (size_t)nt * 16 * 2048 + s * 32);
      bw[s][nt][1] = *(const float4*)(pH + (size_t)nt * 16 * 2048 + s * 32 + 4);
    }
    PIN();
  }

  #pragma unroll
  for (int s = 0; s < 2; ++s) {
    if (s == 0) WAITV(10); else WAITV(0);
    bf16x8 afrag = cvt8(aw[s][0], aw[s][1]);
    #pragma unroll
    for (int nt = 0; nt < 5; ++nt) {
      bf16x8 bfrag = cvt8(bw[s][nt][0], bw[s][nt][1]);
      acc[nt] = MFMA16(afrag, bfrag, acc[nt]);
    }
    PIN();
  }

  #pragma unroll
  for (int nt = 0; nt < 5; ++nt)
    #pragma unroll
    for (int reg = 0; reg < 4; ++reg) {
      int b = m0 + q * 4 + reg;
      int c = nt * 16 + ln;
      float v = acc[nt][reg];
      if (kc == 0) v += r[c];
      atomicAdd(&out[b * 80 + c], v);
    }
}

extern "C" void kernel_launch(void* const* d_in, const int* in_sizes, int n_in,
                              void* d_out, int out_size, void* d_ws, size_t ws_size,
                              hipStream_t stream) {
  const float* feature = (const float*)d_in[0];
  const float* inp     = (const float*)d_in[1];  // [1,80,300]
  const float* A       = (const float*)d_in[2];
  const float* Wgc1    = (const float*)d_in[3];
  const float* Wgc2    = (const float*)d_in[4];
  const float* Wimg    = (const float*)d_in[5];
  const float* bimg    = (const float*)d_in[6];
  const float* Wcls    = (const float*)d_in[7];
  const float* bcls    = (const float*)d_in[8];
  float* out = (float*)d_out;

  char* ws = (char*)d_ws;
  float*  adj = (float*)(ws + 0);         //  80x80    fp32     25,600
  float*  t1  = (float*)(ws + 25600);     //  80x1024  fp32    327,680
  bf16_t* x1b = (bf16_t*)(ws + 353280);   //  80x1024  bf16    163,840
  float*  t2  = (float*)(ws + 517120);    //  80x2048  fp32    655,360
  bf16_t* x2  = (bf16_t*)(ws + 1172480);  //  80x2048  bf16    327,680
  bf16_t* P   = (bf16_t*)(ws + 1500160);  //  80x8000  bf16  1,280,000
  float*  H   = (float*)(ws + 2780160);   //  80x2048  fp32    655,360
  float*  r   = (float*)(ws + 3435520);   //  80       fp32        320
  bf16_t* x0b = (bf16_t*)(ws + 3435840);  //  80x384   bf16     61,440

  hipMemsetAsync(t1, 0, 80 * 1024 * 4, stream);
  hipMemsetAsync(t2, 0, 80 * 2048 * 4, stream);
  hipMemsetAsync(H, 0, 80 * 2048 * 4, stream);
  hipMemsetAsync(out, 0, 1024 * 80 * 4, stream);

  k_adj<<<1, 128, 0, stream>>>(A, adj);
  k_cvt0<<<120, 256, 0, stream>>>(inp, x0b);
  k_gc1m<<<192, 256, 0, stream>>>(x0b, Wgc1, t1);
  k_adjmul_leaky<<<320, 256, 0, stream>>>(adj, t1, x1b);
  k_gc2m<<<256, 256, 0, stream>>>(x1b, Wgc2, t2);
  k_adjmul_bf16<<<640, 256, 0, stream>>>(adj, t2, x2);
  k_clsproj<<<250, 128, 0, stream>>>(Wcls, bcls, x2, P);
  k_rvec<<<80, 256, 0, stream>>>(P, bimg, r);
  k_hmat<<<400, 256, 0, stream>>>(Wimg, P, H);
  k_out<<<512, 256, 0, stream>>>(feature, H, r, out);
}

// Round 7
// 256.502 us; speedup vs baseline: 1.1192x; 1.1109x over previous
//
#include <hip/hip_runtime.h>
#include <hip/hip_bf16.h>

// Shapes: B=1024, C_CLS=80, D_WORD=300 (pad 384), J=8000, IMG_CH=2048
// out = feature @ H^T + r;  H = P @ W_img;  r = P @ b_img
// P = x2 @ W_cls^T + b_cls; x2 = adj @ t2; t2 = x1 @ Wgc2; x1 = leaky(adj @ t1); t1 = x0 @ Wgc1

typedef __bf16 bf16_t;
typedef __bf16 bf16x8 __attribute__((ext_vector_type(8)));
typedef float f32x4 __attribute__((ext_vector_type(4)));

#define MFMA16(a, b, c) __builtin_amdgcn_mfma_f32_16x16x32_bf16((a), (b), (c), 0, 0, 0)

// async global->LDS, 16B per lane; LDS dest is wave-uniform base + lane*16 (linear)
#define GLOAD_LDS16(g, l)                                     \
  __builtin_amdgcn_global_load_lds(                           \
      (const __attribute__((address_space(1))) void*)(g),     \
      (__attribute__((address_space(3))) void*)(l), 16, 0, 0)

// Issue-order pin: vmcnt counting is only valid if machine order == source order.
#define PIN()                                   \
  do {                                          \
    asm volatile("" ::: "memory");              \
    __builtin_amdgcn_sched_barrier(0);          \
  } while (0)

__device__ inline bf16x8 cvt8(float4 a, float4 b) {
  bf16x8 v;
  v[0] = (bf16_t)a.x; v[1] = (bf16_t)a.y; v[2] = (bf16_t)a.z; v[3] = (bf16_t)a.w;
  v[4] = (bf16_t)b.x; v[5] = (bf16_t)b.y; v[6] = (bf16_t)b.z; v[7] = (bf16_t)b.w;
  return v;
}

// ---- fused prep: adj + x0b convert + zero(t2,H,r,out) ----
// replaces k_adj, k_cvt0, and 4 hipMemsetAsync dispatches (13 -> 8 dispatches;
// ~11us launch overhead each per the counter-sum vs dur_us gap).
__global__ __launch_bounds__(256) void k_prep(
    const float* __restrict__ A, const float* __restrict__ inp0,
    float* __restrict__ adj, bf16_t* __restrict__ x0b,
    float* __restrict__ t2, float* __restrict__ H,
    float* __restrict__ r, float* __restrict__ out) {
  int b = blockIdx.x, tid = threadIdx.x;
  if (b == 0) {
    // adj[i][j] = D[i]*D[j]*A[j][i], D = rsqrt(rowsum(A))
    __shared__ float Dv[80];
    if (tid < 80) {
      float s = 0.f;
      #pragma unroll 4
      for (int j = 0; j < 80; ++j) s += A[tid * 80 + j];
      Dv[tid] = rsqrtf(s);
    }
    __syncthreads();
    for (int idx = tid; idx < 6400; idx += 256) {
      int i = idx / 80, j = idx % 80;
      adj[idx] = Dv[i] * Dv[j] * A[j * 80 + i];
    }
  } else if (b <= 120) {
    // x0b[c][k] = bf16(inp0[c][k]) for k<300 else 0 : [80,384]
    int idx = (b - 1) * 256 + tid;
    if (idx < 30720) {
      int c = idx / 384, k = idx % 384;
      x0b[idx] = (k < 300) ? (bf16_t)inp0[c * 300 + k] : (bf16_t)0.f;
    }
  } else {
    // zero t2 (40960 f4), H (40960 f4), out (20480 f4), r (20 f4)
    int t = (b - 121) * 256 + tid;
    const int NT = 39 * 256;
    float4 z = make_float4(0.f, 0.f, 0.f, 0.f);
    for (int i = t; i < 40960; i += NT) ((float4*)t2)[i] = z;
    for (int i = t; i < 40960; i += NT) ((float4*)H)[i] = z;
    for (int i = t; i < 20480; i += NT) ((float4*)out)[i] = z;
    if (t < 20) ((float4*)r)[t] = z;
  }
}

// ---- t1 = x0 @ Wgc1 : [80,1024], K=300 padded to 384 ---- (R3 verbatim)
__global__ __launch_bounds__(256) void k_gc1m(
    const bf16_t* __restrict__ x0b, const float* __restrict__ Wgc1,
    float* __restrict__ t1) {
  int tid = threadIdx.x;
  int w = tid >> 6, l = tid & 63;
  int ln = l & 15, q = l >> 4;
  int n0 = blockIdx.x * 16;

  __shared__ float red[4][80][16];
  f32x4 acc[5] = {};
  for (int ks = 0; ks < 3; ++ks) {
    int kq = w * 96 + ks * 32 + q * 8;
    bf16x8 bfrag;
    #pragma unroll
    for (int jj = 0; jj < 8; ++jj) {
      int k = kq + jj;
      int kc = k < 300 ? k : 299;
      float wv = Wgc1[kc * 1024 + n0 + ln];
      bfrag[jj] = (bf16_t)(k < 300 ? wv : 0.f);
    }
    #pragma unroll
    for (int mt = 0; mt < 5; ++mt) {
      bf16x8 afrag = *(const bf16x8*)(x0b + (size_t)(mt * 16 + ln) * 384 + kq);
      acc[mt] = MFMA16(afrag, bfrag, acc[mt]);
    }
  }
  #pragma unroll
  for (int mt = 0; mt < 5; ++mt)
    #pragma unroll
    for (int reg = 0; reg < 4; ++reg)
      red[w][mt * 16 + q * 4 + reg][ln] = acc[mt][reg];
  __syncthreads();
  for (int o = tid; o < 1280; o += 256) {
    int c = o >> 4, nn = o & 15;
    t1[c * 1024 + n0 + nn] = red[0][c][nn] + red[1][c][nn] + red[2][c][nn] + red[3][c][nn];
  }
}

// ---- x1b = bf16(leaky_relu(adj @ t1, 0.2)) : [80,1024] ---- (R3 verbatim)
__global__ void k_adjmul_leaky(const float* __restrict__ adj, const float* __restrict__ t1,
                               bf16_t* __restrict__ x1b) {
  int idx = blockIdx.x * blockDim.x + threadIdx.x;  // 81920
  int c = idx >> 10, n = idx & 1023;
  const float* ar = adj + c * 80;
  float acc = 0.f;
  #pragma unroll 4
  for (int cc = 0; cc < 80; ++cc) acc += ar[cc] * t1[cc * 1024 + n];
  x1b[idx] = (bf16_t)(acc > 0.f ? acc : 0.2f * acc);
}

// ---- t2 += x1 @ Wgc2 : [80,2048], K=1024 ---- (R3 verbatim)
// grid 512 = 32 n-chunks(64) x 16 k-chunks(64); 2 async 32k stages.
// Pinned issue order: [A0(5)][B0(2)][B1(2)][A1(5)] -> exact counts:
//   wait-B0: after-B0 = B1(2)+A1(5) = 7;  wait-B1: after-B1 = A1(5) = 5.
__global__ __launch_bounds__(256) void k_gc2m(
    const bf16_t* __restrict__ x1b, const float* __restrict__ Wgc2,
    float* __restrict__ t2) {
  int tid = threadIdx.x;
  int w = tid >> 6, l = tid & 63;
  int ln = l & 15, q = l >> 4;
  int nc = blockIdx.x & 31, kc = blockIdx.x >> 5;

  __shared__ float BsF[2 * 2048];  // 2 buffers x 32k x 64n fp32 = 16 KB (linear)
  auto stage = [&](int b, int k0) {
    #pragma unroll
    for (int it = 0; it < 2; ++it) {
      int slot = tid + it * 256;  // 512 slots = 32k x (16 x float4)
      int kr = slot >> 4, nq = slot & 15;
      const float* src = Wgc2 + (size_t)(k0 + kr) * 2048 + nc * 64 + nq * 4;
      float* dst = BsF + b * 2048 + slot * 4;
      GLOAD_LDS16(src, dst);
    }
  };

  int kb = kc * 64;
  bf16x8 a0[5], a1[5];
  #pragma unroll
  for (int mt = 0; mt < 5; ++mt)
    a0[mt] = *(const bf16x8*)(x1b + (size_t)(mt * 16 + ln) * 1024 + kb + q * 8);
  PIN();
  stage(0, kb);
  PIN();
  stage(1, kb + 32);
  PIN();
  #pragma unroll
  for (int mt = 0; mt < 5; ++mt)
    a1[mt] = *(const bf16x8*)(x1b + (size_t)(mt * 16 + ln) * 1024 + kb + 32 + q * 8);
  PIN();

  f32x4 acc[5] = {};
  // stage 0
  asm volatile("s_waitcnt vmcnt(7)" ::: "memory");
  PIN();
  __builtin_amdgcn_s_barrier();
  PIN();
  {
    bf16x8 bfrag;
    #pragma unroll
    for (int jj = 0; jj < 8; ++jj) bfrag[jj] = (bf16_t)BsF[(q * 8 + jj) * 64 + w * 16 + ln];
    #pragma unroll
    for (int mt = 0; mt < 5; ++mt) acc[mt] = MFMA16(a0[mt], bfrag, acc[mt]);
  }
  // stage 1 (no buffer reuse -> no extra barrier between)
  asm volatile("s_waitcnt vmcnt(5)" ::: "memory");
  PIN();
  __builtin_amdgcn_s_barrier();
  PIN();
  {
    bf16x8 bfrag;
    #pragma unroll
    for (int jj = 0; jj < 8; ++jj)
      bfrag[jj] = (bf16_t)BsF[2048 + (q * 8 + jj) * 64 + w * 16 + ln];
    #pragma unroll
    for (int mt = 0; mt < 5; ++mt) acc[mt] = MFMA16(a1[mt], bfrag, acc[mt]);
  }

  #pragma unroll
  for (int mt = 0; mt < 5; ++mt)
    #pragma unroll
    for (int reg = 0; reg < 4; ++reg)
      atomicAdd(&t2[(size_t)(mt * 16 + q * 4 + reg) * 2048 + nc * 64 + w * 16 + ln],
                acc[mt][reg]);
}

// ---- x2 = bf16(adj @ t2) : [80,2048] ---- (R3 verbatim)
__global__ void k_adjmul_bf16(const float* __restrict__ adj, const float* __restrict__ t2,
                              bf16_t* __restrict__ x2) {
  int idx = blockIdx.x * blockDim.x + threadIdx.x;  // 163840
  int c = idx >> 11, n = idx & 2047;
  const float* ar = adj + c * 80;
  float acc = 0.f;
  #pragma unroll 4
  for (int cc = 0; cc < 80; ++cc) acc += ar[cc] * t2[cc * 2048 + n];
  x2[idx] = (bf16_t)acc;
}

// ---- P = bf16(x2 @ W_cls^T + b_cls) : [80,8000]; r[c] += b_img . P[c,:] ---- (R3 verbatim)
__global__ __launch_bounds__(256) void k_clsproj(
    const float* __restrict__ Wcls, const float* __restrict__ bcls,
    const float* __restrict__ bimg, const bf16_t* __restrict__ x2,
    bf16_t* __restrict__ P, float* __restrict__ r) {
  int tid = threadIdx.x;
  int w = tid >> 6, l = tid & 63;
  int ln = l & 15, q = l >> 4;
  int j0 = blockIdx.x * 16;
  size_t jrow = (size_t)(j0 + ln) * 2048;

  __shared__ float red[4][80][16];
  __shared__ float rloc[80];
  if (tid < 80) rloc[tid] = 0.f;

  f32x4 acc[5] = {};
  int kbase = w * 512 + q * 8;
  for (int ks = 0; ks < 16; ++ks) {
    int kq = kbase + ks * 32;
    const float4* bp = (const float4*)(Wcls + jrow + kq);
    float4 b0 = bp[0], b1 = bp[1];
    bf16x8 bfrag = cvt8(b0, b1);
    #pragma unroll
    for (int mt = 0; mt < 5; ++mt) {
      bf16x8 afrag = *(const bf16x8*)(x2 + (size_t)(mt * 16 + ln) * 2048 + kq);
      acc[mt] = MFMA16(afrag, bfrag, acc[mt]);
    }
  }
  #pragma unroll
  for (int mt = 0; mt < 5; ++mt)
    #pragma unroll
    for (int reg = 0; reg < 4; ++reg)
      red[w][mt * 16 + q * 4 + reg][ln] = acc[mt][reg];
  __syncthreads();

  for (int o = tid; o < 1280; o += 256) {
    int c = o >> 4, jj = o & 15;
    float v = red[0][c][jj] + red[1][c][jj] + red[2][c][jj] + red[3][c][jj] + bcls[j0 + jj];
    P[(size_t)c * 8000 + j0 + jj] = (bf16_t)v;
    atomicAdd(&rloc[c], bimg[j0 + jj] * v);
  }
  __syncthreads();
  if (tid < 80) atomicAdd(&r[tid], rloc[tid]);
}

// ---- H[c][n] += sum_j P[c][j]*W_img[j][n] ---- (R3 verbatim: barrier-free
// wave-private LDS ring-3, global_load_lds, counted vmcnt; grid 400)
__global__ __launch_bounds__(256) void k_hmat(
    const float* __restrict__ Wimg, const bf16_t* __restrict__ P, float* __restrict__ H) {
  int tid = threadIdx.x;
  int w = tid >> 6, l = tid & 63;
  int ln = l & 15, q = l >> 4;
  int jc = blockIdx.x >> 4, ncg = blockIdx.x & 15;
  int jbase = jc * 320;
  int n0 = (ncg * 4 + w) * 32;

  __shared__ float Bs[4 * 3 * 1024];  // 4 waves x ring-3 x (32j x 32n fp32) = 48 KB
  float* Bw = Bs + w * 3072;

  auto stage = [&](int buf, int jt) {
    #pragma unroll
    for (int it = 0; it < 4; ++it) {
      int row = it * 8 + (l >> 3);          // j-row 0..31
      const float* src = Wimg + (size_t)(jt + row) * 2048 + n0 + (l & 7) * 4;
      float* dst = Bw + buf * 1024 + it * 256 + l * 4;  // linear: lane*16B
      GLOAD_LDS16(src, dst);
    }
  };
  auto loadA = [&](bf16x8* a, int j0) {
    #pragma unroll
    for (int mt = 0; mt < 5; ++mt)
      a[mt] = *(const bf16x8*)(P + (size_t)(mt * 16 + ln) * 8000 + j0 + q * 8);
  };

  f32x4 acc[5][2] = {};
  bf16x8 aCur[5], aNxt[5];

  loadA(aCur, jbase);      // A(0)
  PIN();
  stage(0, jbase);         // B(0)
  PIN();
  stage(1, jbase + 32);    // B(1)
  PIN();

  #pragma unroll
  for (int s = 0; s < 10; ++s) {
    if (s < 9) {
      loadA(aNxt, jbase + (s + 1) * 32);   // A(s+1)
      PIN();
    }
    if (s < 8) {
      stage((s + 2) % 3, jbase + (s + 2) * 32);  // B(s+2)
      PIN();
    }
    if (s < 8)       asm volatile("s_waitcnt vmcnt(13)" ::: "memory");
    else if (s == 8) asm volatile("s_waitcnt vmcnt(9)"  ::: "memory");
    else             asm volatile("s_waitcnt vmcnt(5)"  ::: "memory");
    PIN();  // no barrier — buffer is wave-private
    const float* Bc = Bw + (s % 3) * 1024;
    bf16x8 bfrag[2];
    #pragma unroll
    for (int nt = 0; nt < 2; ++nt)
      #pragma unroll
      for (int jj = 0; jj < 8; ++jj)
        bfrag[nt][jj] = (bf16_t)Bc[(q * 8 + jj) * 32 + nt * 16 + ln];
    #pragma unroll
    for (int mt = 0; mt < 5; ++mt)
      #pragma unroll
      for (int nt = 0; nt < 2; ++nt)
        acc[mt][nt] = MFMA16(aCur[mt], bfrag[nt], acc[mt][nt]);
    PIN();  // keep cvt/MFMA ahead of next iter's restage of buf[s%3]
    if (s < 9) {
      #pragma unroll
      for (int mt = 0; mt < 5; ++mt) aCur[mt] = aNxt[mt];
    }
  }

  #pragma unroll
  for (int mt = 0; mt < 5; ++mt)
    #pragma unroll
    for (int nt = 0; nt < 2; ++nt)
      #pragma unroll
      for (int reg = 0; reg < 4; ++reg)
        atomicAdd(&H[(size_t)(mt * 16 + q * 4 + reg) * 2048 + n0 + nt * 16 + ln],
                  acc[mt][nt][reg]);
}

// ---- out[b][c] += sum_k feature[b][k]*H[c][k]  (+ r[c] once) ---- (R3 verbatim)
__global__ __launch_bounds__(256) void k_out(
    const float* __restrict__ feat, const float* __restrict__ H,
    const float* __restrict__ r, float* __restrict__ out) {
  int tid = threadIdx.x;
  int w = tid >> 6, l = tid & 63;
  int ln = l & 15, q = l >> 4;
  int mg = blockIdx.x & 15, kc = blockIdx.x >> 4;  // kc 0..31, 64 k each
  int m0 = mg * 64 + w * 16;
  size_t frow = (size_t)(m0 + ln) * 2048;

  f32x4 acc[5] = {};
  int kbase = kc * 64 + q * 8;
  #pragma unroll
  for (int ks = 0; ks < 2; ++ks) {
    int kq = kbase + ks * 32;
    const float4* ap = (const float4*)(feat + frow + kq);
    bf16x8 afrag = cvt8(ap[0], ap[1]);
    #pragma unroll
    for (int nt = 0; nt < 5; ++nt) {
      const float4* hp = (const float4*)(H + (size_t)(nt * 16 + ln) * 2048 + kq);
      bf16x8 bfrag = cvt8(hp[0], hp[1]);
      acc[nt] = MFMA16(afrag, bfrag, acc[nt]);
    }
  }
  #pragma unroll
  for (int nt = 0; nt < 5; ++nt)
    #pragma unroll
    for (int reg = 0; reg < 4; ++reg) {
      int b = m0 + q * 4 + reg;
      int c = nt * 16 + ln;
      float v = acc[nt][reg];
      if (kc == 0) v += r[c];
      atomicAdd(&out[b * 80 + c], v);
    }
}

extern "C" void kernel_launch(void* const* d_in, const int* in_sizes, int n_in,
                              void* d_out, int out_size, void* d_ws, size_t ws_size,
                              hipStream_t stream) {
  const float* feature = (const float*)d_in[0];
  const float* inp     = (const float*)d_in[1];  // [1,80,300]
  const float* A       = (const float*)d_in[2];
  const float* Wgc1    = (const float*)d_in[3];
  const float* Wgc2    = (const float*)d_in[4];
  const float* Wimg    = (const float*)d_in[5];
  const float* bimg    = (const float*)d_in[6];
  const float* Wcls    = (const float*)d_in[7];
  const float* bcls    = (const float*)d_in[8];
  float* out = (float*)d_out;

  char* ws = (char*)d_ws;
  float*  adj = (float*)(ws + 0);         //  80x80    fp32     25,600
  float*  t1  = (float*)(ws + 25600);     //  80x1024  fp32    327,680
  bf16_t* x1b = (bf16_t*)(ws + 353280);   //  80x1024  bf16    163,840
  float*  t2  = (float*)(ws + 517120);    //  80x2048  fp32    655,360
  bf16_t* x2  = (bf16_t*)(ws + 1172480);  //  80x2048  bf16    327,680
  bf16_t* P   = (bf16_t*)(ws + 1500160);  //  80x8000  bf16  1,280,000
  float*  H   = (float*)(ws + 2780160);   //  80x2048  fp32    655,360
  float*  r   = (float*)(ws + 3435520);   //  80       fp32        320
  bf16_t* x0b = (bf16_t*)(ws + 3435840);  //  80x384   bf16     61,440

  // 8 dispatches total (was 13: 9 kernels + 4 memsets)
  k_prep<<<160, 256, 0, stream>>>(A, inp, adj, x0b, t2, H, r, out);
  k_gc1m<<<64, 256, 0, stream>>>(x0b, Wgc1, t1);
  k_adjmul_leaky<<<320, 256, 0, stream>>>(adj, t1, x1b);
  k_gc2m<<<512, 256, 0, stream>>>(x1b, Wgc2, t2);
  k_adjmul_bf16<<<640, 256, 0, stream>>>(adj, t2, x2);
  k_clsproj<<<500, 256, 0, stream>>>(Wcls, bcls, bimg, x2, P, r);
  k_hmat<<<400, 256, 0, stream>>>(Wimg, P, H);
  k_out<<<512, 256, 0, stream>>>(feature, H, r, out);
}